// Round 6
// baseline (227.693 us; speedup 1.0000x reference)
//
#include <hip/hip_runtime.h>

#define B_SZ 256
#define P_SZ 128
#define F_SZ 7
#define H_SZ 256
#define KNB  16
#define CH_OUT 264   // H + F + 1

typedef __bf16 bf16x8 __attribute__((ext_vector_type(8)));
typedef __bf16 bf16x4 __attribute__((ext_vector_type(4)));
typedef float  f32x4  __attribute__((ext_vector_type(4)));

// ---------------------------------------------------------------------------
// Grid = 512: block (b, ph) handles batch b, points ph*64..+63. 8 waves.
// LDS = 56 KB -> 2 blocks/CU; launch_bounds(512,2) -> 128-VGPR cap (4 waves/EU
// with 2 blocks; the (512,4) variant capped at 64 VGPR and spilled ~70 MB).
//  KNN: waves scan candidate-quarters (waves 4-7 duplicate 0-3's quarters and
//       publish lists); waves 0-3 do two f64-min/max merge stages; exact
//       (dist,idx) keys packed as f64 = dbits*128+j (exact, 38 bits).
//  Main loop (16 iters x 4 points): phase 1 = 2 waves per point (8 W1 tiles
//       each, bias folded into W1 row k=14); phase 2 = wave owns 2 n-tiles,
//       W2 register-resident, 4 pts/wave from LDS.
//  sH1 layout is chunk-major [pt][kc=k/8][m=16][8el]: phase-2 b128 reads hit
//  bank 4*c16 (conflict-free per 8-lane phase); phase-1 b64 stores 2-way.
// ---------------------------------------------------------------------------
__global__ __launch_bounds__(512, 2) void edgeconv_fused(
    const float* __restrict__ ev, const float* __restrict__ W1,
    const float* __restrict__ b1, const float* __restrict__ W2,
    const float* __restrict__ b2, float* __restrict__ out) {
  const int b    = blockIdx.x >> 1;
  const int ph   = blockIdx.x & 1;
  const int tid  = threadIdx.x;
  const int lane = tid & 63;
  const int wave = tid >> 6;         // 0..7
  const int qd   = lane >> 4;        // 0..3
  const int c16  = lane & 15;

  __shared__ float sFeats[P_SZ][8];                     // 4 KB (full batch)
  __shared__ __align__(16) __bf16 sW1[16][64][8];       // 16 KB, B-frag order
  __shared__ unsigned short sIdx[64][KNB];              // 2 KB (this block's pts)
  // union: knn lists 4*17*64*8 = 34816 B >= sH1 4*32*16*8*2 = 32768 B
  __shared__ __align__(16) unsigned char sU[4 * 17 * 64 * 8];
  double* lists = (double*)sU;                          // [quarter][17][64]
  __bf16* sH1   = (__bf16*)sU;                          // [pt][kc=32][m=16][8]

  // ---- stage events + W1 frags (bias folded in at k=14) ----
  if (tid < 2 * P_SZ)
    ((float4*)&sFeats[0][0])[tid] = ((const float4*)(ev + (size_t)b * P_SZ * 8))[tid];
  for (int en = tid; en < 1024; en += 512) {
    const int t = en >> 6, ln = en & 63;
    const int qq = ln >> 4, cc = ln & 15;
    const int n = t * 16 + cc;
    bf16x8 v;
#pragma unroll
    for (int j = 0; j < 8; ++j) {
      const int k = qq * 8 + j;
      float w = 0.0f;
      if (k < 2 * F_SZ) w = W1[k * H_SZ + n];
      else if (k == 2 * F_SZ) w = b1[n];   // bias row, edge supplies 1.0
      v[j] = (__bf16)w;
    }
    *(bf16x8*)&sW1[t][ln][0] = v;
  }
  __syncthreads();

  // ---- feats passthrough + mask channel (needs only sFeats) ----
  {
    const int pl = tid >> 3, ch = tid & 7;       // 64 pts x 8 ch
    const int pg = ph * 64 + pl;
    const float msk = sFeats[pg][7];
    float v;
    if (ch < 7) {
      float fv = sFeats[pg][ch];
      fv = fv > 0.0f ? fv : 0.2f * fv;
      v = (msk > 0.5f ? 1.0f : 0.0f) * fv;
    } else {
      v = msk;
    }
    out[((size_t)(b * P_SZ + pg)) * CH_OUT + H_SZ + ch] = v;
  }

  // =====================  KNN (f64 min/max network)  =====================
  // lane-point = ph*64 + lane; quarter q = wave&3 scans cands q*32..+31.
  const int q  = wave & 3;
  const int ip = ph * 64 + lane;
  const float xi = sFeats[ip][0], yi = sFeats[ip][1];

  double arr[17];
#pragma unroll
  for (int t = 0; t < 17; ++t) arr[t] = 1.0e300;

#pragma unroll 1
  for (int cc = 0; cc < 32; ++cc) {
    const int j = q * 32 + cc;                 // wave-uniform -> LDS broadcast
    const float2 cj = *(const float2*)&sFeats[j][0];
    const float mj  = sFeats[j][7];
    const float dx = xi - cj.x, dy = yi - cj.y;
    const float d  = sqrtf(dx * dx + dy * dy);
    const float dd = (mj > 0.5f) ? d : 3.0e38f;
    double key = (double)__float_as_uint(dd) * 128.0 + (double)j;  // exact
#pragma unroll
    for (int t = 0; t < 17; ++t) {             // branchless sorted insert
      const double lo = fmin(arr[t], key);
      key    = fmax(arr[t], key);
      arr[t] = lo;
    }
  }

  // waves 4-7 publish their quarter's list
  if (wave >= 4) {
#pragma unroll 1
    for (int t = 0; t < 17; ++t) lists[(q * 17 + t) * 64 + lane] = arr[t];
  }
  __syncthreads();
  if (wave < 4) {            // stage 1: merge quarter q^1
#pragma unroll 1
    for (int t = 0; t < 17; ++t) {
      double key = lists[((q ^ 1) * 17 + t) * 64 + lane];
#pragma unroll
      for (int u = 0; u < 17; ++u) {
        const double lo = fmin(arr[u], key);
        key    = fmax(arr[u], key);
        arr[u] = lo;
      }
    }
  }
  __syncthreads();
  if (wave < 4) {            // publish stage-1 result {q, q^1}
#pragma unroll 1
    for (int t = 0; t < 17; ++t) lists[(q * 17 + t) * 64 + lane] = arr[t];
  }
  __syncthreads();
  if (wave < 4) {            // stage 2: merge {q^2, q^3}; write sIdx slice
#pragma unroll 1
    for (int t = 0; t < 17; ++t) {
      double key = lists[((q ^ 2) * 17 + t) * 64 + lane];
#pragma unroll
      for (int u = 0; u < 17; ++u) {
        const double lo = fmin(arr[u], key);
        key    = fmax(arr[u], key);
        arr[u] = lo;
      }
    }
    // all 4 waves hold identical top-17; wave q writes ranks q*4..q*4+3
#pragma unroll
    for (int u = 0; u < 4; ++u) {
      const unsigned long long kv = (unsigned long long)arr[1 + q * 4 + u];
      sIdx[lane][q * 4 + u] = (unsigned short)(kv & 127);
    }
  }
  __syncthreads();   // sIdx ready; lists region free for sH1

  // ---- W2 B-fragments: 2 n-tiles x 8 k-steps (64 VGPRs), after KNN so
  // arr[17] is dead before these go live (stay under the 128-VGPR cap).
  const int t0 = wave * 2;
  bf16x8 w2f[2][8];
  float  b2v[2];
#pragma unroll
  for (int tt = 0; tt < 2; ++tt) {
    const int n = (t0 + tt) * 16 + c16;
#pragma unroll
    for (int kk = 0; kk < 8; ++kk) {
#pragma unroll
      for (int j = 0; j < 8; ++j)
        w2f[tt][kk][j] = (__bf16)W2[(kk * 32 + qd * 8 + j) * H_SZ + n];
    }
    b2v[tt] = b2[n];
  }

  // ===========================  edge-MLP main loop  ==========================
#pragma unroll 1
  for (int it = 0; it < 16; ++it) {
    const int pl = it * 4 + (wave >> 1);   // local point 0..63
    const int pg = ph * 64 + pl;           // global row in sFeats
    const int hh = wave & 1;               // W1-tile half

    // ---- Phase 1 (transposed GEMM1): this wave does 8 of 16 n-tiles ----
    {
      const int nb = sIdx[pl][c16];
      const float* cf = &sFeats[pg][0];
      float4 nf0 = *(const float4*)&sFeats[nb][0];
      float4 nf1 = *(const float4*)&sFeats[nb][4];
      const float nfv[8] = {nf0.x, nf0.y, nf0.z, nf0.w, nf1.x, nf1.y, nf1.z, nf1.w};
      float ed[8];
      if (qd == 0) {        // k = 0..7: central[0..6], (neigh-central)[0]
#pragma unroll
        for (int j = 0; j < 7; ++j) ed[j] = cf[j];
        ed[7] = nfv[0] - cf[0];
      } else if (qd == 1) { // k = 8..15: (n-c)[1..6], bias-1.0 at k=14, pad
#pragma unroll
        for (int j = 0; j < 6; ++j) ed[j] = nfv[j + 1] - cf[j + 1];
        ed[6] = 1.0f; ed[7] = 0.0f;
      } else {              // k = 16..31: zero pad
#pragma unroll
        for (int j = 0; j < 8; ++j) ed[j] = 0.0f;
      }
      bf16x8 af;
#pragma unroll
      for (int j = 0; j < 8; ++j) af[j] = (__bf16)ed[j];

#pragma unroll
      for (int t = 0; t < 8; ++t) {
        const int tt = hh * 8 + t;
        bf16x8 w1t = *(const bf16x8*)&sW1[tt][lane][0];
        f32x4 acc = {0.0f, 0.0f, 0.0f, 0.0f};
        acc = __builtin_amdgcn_mfma_f32_16x16x32_bf16(w1t, af, acc, 0, 0, 0);
        bf16x4 hv;
#pragma unroll
        for (int rr = 0; rr < 4; ++rr) {
          float h = acc[rr];
          h = h > 0.0f ? h : 0.0f;
          hv[rr] = (__bf16)h;
        }
        // chunk-major: n = tt*16 + qd*4 + rr -> kc = tt*2 + (qd>>1), off = (qd&1)*4
        const int kc = tt * 2 + (qd >> 1);
        *(bf16x4*)&sH1[(((size_t)(wave >> 1) * 32 + kc) * 16 + c16) * 8 + (qd & 1) * 4] = hv;
      }
    }
    __syncthreads();

    // ---- Phase 2: h1(16x256) @ W2; wave owns tiles {2w,2w+1}, 4 pts ----
    f32x4 acc2[4][2] = {};
#pragma unroll
    for (int kk = 0; kk < 8; ++kk) {
      bf16x8 a[4];
#pragma unroll
      for (int pp = 0; pp < 4; ++pp)   // A[m=c16][k = kk*32+qd*8..+7] -> kc = kk*4+qd
        a[pp] = *(const bf16x8*)&sH1[(((size_t)pp * 32 + kk * 4 + qd) * 16 + c16) * 8];
#pragma unroll
      for (int pp = 0; pp < 4; ++pp) {
        acc2[pp][0] = __builtin_amdgcn_mfma_f32_16x16x32_bf16(a[pp], w2f[0][kk], acc2[pp][0], 0, 0, 0);
        acc2[pp][1] = __builtin_amdgcn_mfma_f32_16x16x32_bf16(a[pp], w2f[1][kk], acc2[pp][1], 0, 0, 0);
      }
    }

#pragma unroll
    for (int pp = 0; pp < 4; ++pp) {
      const int ptg = ph * 64 + it * 4 + pp;
      const float msk  = sFeats[ptg][7];
      const float keep = (msk > 0.5f) ? 1.0f : 0.0f;
      float sarr[2];
#pragma unroll
      for (int tt = 0; tt < 2; ++tt) {
        float s = 0.0f;
#pragma unroll
        for (int rr = 0; rr < 4; ++rr) {
          float h = acc2[pp][tt][rr] + b2v[tt];
          s += (h > 0.0f ? h : 0.0f);
        }
        s += __shfl_xor(s, 16, 64);   // sum 4 quads -> full 16-row sum
        s += __shfl_xor(s, 32, 64);
        sarr[tt] = s;
      }
      if (lane < 32) {                // half-wave contiguous 128 B store
        const float v = (lane >> 4) ? sarr[1] : sarr[0];
        const float agg = v * (1.0f / 16.0f);
        const float o = agg > 0.0f ? agg : 0.2f * agg;
        out[((size_t)(b * P_SZ + ptg)) * CH_OUT + t0 * 16 + lane] = keep * o;
      }
    }
    __syncthreads();   // sH1 fully consumed before next iter's writes
  }
}

// ---------------------------------------------------------------------------
extern "C" void kernel_launch(void* const* d_in, const int* in_sizes, int n_in,
                              void* d_out, int out_size, void* d_ws, size_t ws_size,
                              hipStream_t stream) {
  const float* ev = (const float*)d_in[0];
  const float* W1 = (const float*)d_in[1];
  const float* b1 = (const float*)d_in[2];
  const float* W2 = (const float*)d_in[3];
  const float* b2 = (const float*)d_in[4];
  float* out = (float*)d_out;

  edgeconv_fused<<<B_SZ * 2, 512, 0, stream>>>(ev, W1, b1, W2, b2, out);
}

// Round 7
// 171.582 us; speedup vs baseline: 1.3270x; 1.3270x over previous
//
#include <hip/hip_runtime.h>

#define B_SZ 256
#define P_SZ 128
#define F_SZ 7
#define H_SZ 256
#define KNB  16
#define CH_OUT 264   // H + F + 1

typedef __bf16 bf16x8 __attribute__((ext_vector_type(8)));
typedef __bf16 bf16x4 __attribute__((ext_vector_type(4)));
typedef float  f32x4  __attribute__((ext_vector_type(4)));

// ---------------------------------------------------------------------------
// Grid = 512: block (b, ph) handles batch b, points ph*64..+63. 8 waves.
// LDS = 56 KB -> 2 blocks/CU; launch_bounds(512,4) -> 128-VGPR cap.
// CRITICAL: every loop that indexes the KNN register array arr[] must be
// FULLY UNROLLED (constant indices) or the compiler demotes arr to scratch
// (rounds 4-6: +40 MB WRITE_SIZE of spill traffic).
//  KNN: waves scan candidate-quarters (waves 4-7 duplicate 0-3's quarters and
//       publish lists); waves 0-3 do two f64-min/max merge stages; exact
//       (dist,idx) keys packed as f64 = dbits*128+j (exact, 38 bits).
//  Main loop (16 iters x 4 points): phase 1 = 2 waves per point (8 W1 tiles
//       each, bias folded into W1 row k=14); phase 2 = wave owns 2 n-tiles,
//       W2 register-resident, 4 pts/wave from LDS.
//  sH1 chunk-major [pt][kc=k/8][m=16][8el]: phase-2 b128 reads conflict-free,
//  phase-1 b64 stores 2-way (free). Confirmed: conflicts 12.7M -> 4.3M.
// ---------------------------------------------------------------------------
__global__ __launch_bounds__(512, 4) void edgeconv_fused(
    const float* __restrict__ ev, const float* __restrict__ W1,
    const float* __restrict__ b1, const float* __restrict__ W2,
    const float* __restrict__ b2, float* __restrict__ out) {
  const int b    = blockIdx.x >> 1;
  const int ph   = blockIdx.x & 1;
  const int tid  = threadIdx.x;
  const int lane = tid & 63;
  const int wave = tid >> 6;         // 0..7
  const int qd   = lane >> 4;        // 0..3
  const int c16  = lane & 15;

  __shared__ float sFeats[P_SZ][8];                     // 4 KB (full batch)
  __shared__ __align__(16) __bf16 sW1[16][64][8];       // 16 KB, B-frag order
  __shared__ unsigned short sIdx[64][KNB];              // 2 KB (this block's pts)
  // union: knn lists 4*17*64*8 = 34816 B >= sH1 4*32*16*8*2 = 32768 B
  __shared__ __align__(16) unsigned char sU[4 * 17 * 64 * 8];
  double* lists = (double*)sU;                          // [quarter][17][64]
  __bf16* sH1   = (__bf16*)sU;                          // [pt][kc=32][m=16][8]

  // ---- stage events + W1 frags (bias folded in at k=14) ----
  if (tid < 2 * P_SZ)
    ((float4*)&sFeats[0][0])[tid] = ((const float4*)(ev + (size_t)b * P_SZ * 8))[tid];
  for (int en = tid; en < 1024; en += 512) {
    const int t = en >> 6, ln = en & 63;
    const int qq = ln >> 4, cc = ln & 15;
    const int n = t * 16 + cc;
    bf16x8 v;
#pragma unroll
    for (int j = 0; j < 8; ++j) {
      const int k = qq * 8 + j;
      float w = 0.0f;
      if (k < 2 * F_SZ) w = W1[k * H_SZ + n];
      else if (k == 2 * F_SZ) w = b1[n];   // bias row, edge supplies 1.0
      v[j] = (__bf16)w;
    }
    *(bf16x8*)&sW1[t][ln][0] = v;
  }
  __syncthreads();

  // ---- feats passthrough + mask channel (needs only sFeats) ----
  {
    const int pl = tid >> 3, ch = tid & 7;       // 64 pts x 8 ch
    const int pg = ph * 64 + pl;
    const float msk = sFeats[pg][7];
    float v;
    if (ch < 7) {
      float fv = sFeats[pg][ch];
      fv = fv > 0.0f ? fv : 0.2f * fv;
      v = (msk > 0.5f ? 1.0f : 0.0f) * fv;
    } else {
      v = msk;
    }
    out[((size_t)(b * P_SZ + pg)) * CH_OUT + H_SZ + ch] = v;
  }

  // =====================  KNN (f64 min/max network)  =====================
  // lane-point = ph*64 + lane; quarter q = wave&3 scans cands q*32..+31.
  const int q  = wave & 3;
  const int ip = ph * 64 + lane;
  const float xi = sFeats[ip][0], yi = sFeats[ip][1];

  double arr[17];
#pragma unroll
  for (int t = 0; t < 17; ++t) arr[t] = 1.0e300;

#pragma unroll 1
  for (int cc = 0; cc < 32; ++cc) {            // rolled: inner net has const idx
    const int j = q * 32 + cc;                 // wave-uniform -> LDS broadcast
    const float2 cj = *(const float2*)&sFeats[j][0];
    const float mj  = sFeats[j][7];
    const float dx = xi - cj.x, dy = yi - cj.y;
    const float d  = sqrtf(dx * dx + dy * dy);
    const float dd = (mj > 0.5f) ? d : 3.0e38f;
    double key = (double)__float_as_uint(dd) * 128.0 + (double)j;  // exact
#pragma unroll
    for (int t = 0; t < 17; ++t) {             // branchless sorted insert
      const double lo = fmin(arr[t], key);
      key    = fmax(arr[t], key);
      arr[t] = lo;
    }
  }

  // waves 4-7 publish their quarter's list (FULL unroll: const arr idx)
  if (wave >= 4) {
#pragma unroll
    for (int t = 0; t < 17; ++t) lists[(q * 17 + t) * 64 + lane] = arr[t];
  }
  __syncthreads();
  if (wave < 4) {            // stage 1: merge quarter q^1
#pragma unroll
    for (int t = 0; t < 17; ++t) {
      double key = lists[((q ^ 1) * 17 + t) * 64 + lane];
#pragma unroll
      for (int u = 0; u < 17; ++u) {
        const double lo = fmin(arr[u], key);
        key    = fmax(arr[u], key);
        arr[u] = lo;
      }
    }
  }
  __syncthreads();
  if (wave < 4) {            // publish stage-1 result {q, q^1}
#pragma unroll
    for (int t = 0; t < 17; ++t) lists[(q * 17 + t) * 64 + lane] = arr[t];
  }
  __syncthreads();
  if (wave < 4) {            // stage 2: merge {q^2, q^3}
#pragma unroll
    for (int t = 0; t < 17; ++t) {
      double key = lists[((q ^ 2) * 17 + t) * 64 + lane];
#pragma unroll
      for (int u = 0; u < 17; ++u) {
        const double lo = fmin(arr[u], key);
        key    = fmax(arr[u], key);
        arr[u] = lo;
      }
    }
  }
  // waves with q==0 hold the full top-17; write all 16 ranks (const arr idx)
  if (wave < 4 && q == 0) {
#pragma unroll
    for (int t = 1; t < 17; ++t) {
      const unsigned long long kv = (unsigned long long)arr[t];
      sIdx[lane][t - 1] = (unsigned short)(kv & 127);
    }
  }
  __syncthreads();   // sIdx ready; lists region free for sH1

  // ---- W2 B-fragments: 2 n-tiles x 8 k-steps (64 VGPRs), after KNN so
  // arr[17] is dead before these go live (stay under the 128-VGPR cap).
  const int t0 = wave * 2;
  bf16x8 w2f[2][8];
  float  b2v[2];
#pragma unroll
  for (int tt = 0; tt < 2; ++tt) {
    const int n = (t0 + tt) * 16 + c16;
#pragma unroll
    for (int kk = 0; kk < 8; ++kk) {
#pragma unroll
      for (int j = 0; j < 8; ++j)
        w2f[tt][kk][j] = (__bf16)W2[(kk * 32 + qd * 8 + j) * H_SZ + n];
    }
    b2v[tt] = b2[n];
  }

  // ===========================  edge-MLP main loop  ==========================
#pragma unroll 1
  for (int it = 0; it < 16; ++it) {
    const int pl = it * 4 + (wave >> 1);   // local point 0..63
    const int pg = ph * 64 + pl;           // global row in sFeats
    const int hh = wave & 1;               // W1-tile half

    // ---- Phase 1 (transposed GEMM1): this wave does 8 of 16 n-tiles ----
    {
      const int nb = sIdx[pl][c16];
      const float* cf = &sFeats[pg][0];
      float4 nf0 = *(const float4*)&sFeats[nb][0];
      float4 nf1 = *(const float4*)&sFeats[nb][4];
      const float nfv[8] = {nf0.x, nf0.y, nf0.z, nf0.w, nf1.x, nf1.y, nf1.z, nf1.w};
      float ed[8];
      if (qd == 0) {        // k = 0..7: central[0..6], (neigh-central)[0]
#pragma unroll
        for (int j = 0; j < 7; ++j) ed[j] = cf[j];
        ed[7] = nfv[0] - cf[0];
      } else if (qd == 1) { // k = 8..15: (n-c)[1..6], bias-1.0 at k=14, pad
#pragma unroll
        for (int j = 0; j < 6; ++j) ed[j] = nfv[j + 1] - cf[j + 1];
        ed[6] = 1.0f; ed[7] = 0.0f;
      } else {              // k = 16..31: zero pad
#pragma unroll
        for (int j = 0; j < 8; ++j) ed[j] = 0.0f;
      }
      bf16x8 af;
#pragma unroll
      for (int j = 0; j < 8; ++j) af[j] = (__bf16)ed[j];

#pragma unroll
      for (int t = 0; t < 8; ++t) {
        const int tt = hh * 8 + t;
        bf16x8 w1t = *(const bf16x8*)&sW1[tt][lane][0];
        f32x4 acc = {0.0f, 0.0f, 0.0f, 0.0f};
        acc = __builtin_amdgcn_mfma_f32_16x16x32_bf16(w1t, af, acc, 0, 0, 0);
        bf16x4 hv;
#pragma unroll
        for (int rr = 0; rr < 4; ++rr) {
          float h = acc[rr];
          h = h > 0.0f ? h : 0.0f;
          hv[rr] = (__bf16)h;
        }
        // chunk-major: n = tt*16 + qd*4 + rr -> kc = tt*2 + (qd>>1), off = (qd&1)*4
        const int kc = tt * 2 + (qd >> 1);
        *(bf16x4*)&sH1[(((size_t)(wave >> 1) * 32 + kc) * 16 + c16) * 8 + (qd & 1) * 4] = hv;
      }
    }
    __syncthreads();

    // ---- Phase 2: h1(16x256) @ W2; wave owns tiles {2w,2w+1}, 4 pts ----
    f32x4 acc2[4][2] = {};
#pragma unroll
    for (int kk = 0; kk < 8; ++kk) {
      bf16x8 a[4];
#pragma unroll
      for (int pp = 0; pp < 4; ++pp)   // A[m=c16][k = kk*32+qd*8..+7] -> kc = kk*4+qd
        a[pp] = *(const bf16x8*)&sH1[(((size_t)pp * 32 + kk * 4 + qd) * 16 + c16) * 8];
#pragma unroll
      for (int pp = 0; pp < 4; ++pp) {
        acc2[pp][0] = __builtin_amdgcn_mfma_f32_16x16x32_bf16(a[pp], w2f[0][kk], acc2[pp][0], 0, 0, 0);
        acc2[pp][1] = __builtin_amdgcn_mfma_f32_16x16x32_bf16(a[pp], w2f[1][kk], acc2[pp][1], 0, 0, 0);
      }
    }

#pragma unroll
    for (int pp = 0; pp < 4; ++pp) {
      const int ptg = ph * 64 + it * 4 + pp;
      const float msk  = sFeats[ptg][7];
      const float keep = (msk > 0.5f) ? 1.0f : 0.0f;
      float sarr[2];
#pragma unroll
      for (int tt = 0; tt < 2; ++tt) {
        float s = 0.0f;
#pragma unroll
        for (int rr = 0; rr < 4; ++rr) {
          float h = acc2[pp][tt][rr] + b2v[tt];
          s += (h > 0.0f ? h : 0.0f);
        }
        s += __shfl_xor(s, 16, 64);   // sum 4 quads -> full 16-row sum
        s += __shfl_xor(s, 32, 64);
        sarr[tt] = s;
      }
      if (lane < 32) {                // half-wave contiguous 128 B store
        const float v = (lane >> 4) ? sarr[1] : sarr[0];
        const float agg = v * (1.0f / 16.0f);
        const float o = agg > 0.0f ? agg : 0.2f * agg;
        out[((size_t)(b * P_SZ + ptg)) * CH_OUT + t0 * 16 + lane] = keep * o;
      }
    }
    __syncthreads();   // sH1 fully consumed before next iter's writes
  }
}

// ---------------------------------------------------------------------------
extern "C" void kernel_launch(void* const* d_in, const int* in_sizes, int n_in,
                              void* d_out, int out_size, void* d_ws, size_t ws_size,
                              hipStream_t stream) {
  const float* ev = (const float*)d_in[0];
  const float* W1 = (const float*)d_in[1];
  const float* b1 = (const float*)d_in[2];
  const float* W2 = (const float*)d_in[3];
  const float* b2 = (const float*)d_in[4];
  float* out = (float*)d_out;

  edgeconv_fused<<<B_SZ * 2, 512, 0, stream>>>(ev, W1, b1, W2, b2, out);
}